// Round 4
// baseline (486.438 us; speedup 1.0000x reference)
//
#include <hip/hip_runtime.h>
#include <cstdint>
#include <cstddef>

// FeedForward: GroupNorm(8) -> conv1x1 C->2C -> GELU(exact) -> conv1x1 2C->C -> +x
// B=16, C=512, L=4096. ALL I/O FP32. Internal: bf16 MFMA, fp32 accum.
//
// R8 = R7 + endpgm-drain fix (R7 bench died at container level, no counters):
//  - gemm_core256 now drains vmcnt(0) AFTER the pipeline loop. R7 ended the
//    kernel with up to 8 global_load_lds in flight (counted-vmcnt pipeline
//    never drains in-loop); an in-flight LDS-DMA landing after workgroup exit
//    (LDS deallocated/reassigned) can fault the GPU -> container failure.
//    R6 was implicitly protected by its final __syncthreads drain.
// R7 structure (kept): both GEMMs on 256x256-tile, 8-wave (512 thr), 128KB
// LDS, 4-phase schedule (T3+T4+T5): 2 buf x 2 K-halves per operand, every
// phase stages one half (2 gloads), counted s_waitcnt vmcnt(8) at phases 2&4
// only, s_setprio(1) around each 16-MFMA cluster, in-half XOR slot swizzle.
// R5/R6 kept: branchless A&S erf GELU, swapped mfma(bb,af) vectorized
// epilogues, XCD-aware block swizzles, async staging via global_load_lds.

typedef unsigned short u16;
typedef unsigned int u32;
typedef __attribute__((ext_vector_type(8))) __bf16 bf16x8;
typedef __attribute__((ext_vector_type(4))) float floatx4;

#define BKK 64

__device__ __forceinline__ u16 f2bf(float f) {
    union { float f; u32 u; } v; v.f = f;
    u32 u = v.u;
    return (u16)((u + 0x7fffu + ((u >> 16) & 1u)) >> 16);  // RNE
}

// GELU(v) = 0.5 v (1 + erf(v/sqrt(2))); erf via A&S 7.1.26, |err| <= 1.5e-7.
__device__ __forceinline__ float gelu_exact(float v) {
    const float x = fabsf(v) * 0.70710678118654752f;
    const float t = __builtin_amdgcn_rcpf(fmaf(0.3275911f, x, 1.0f));
    float p = fmaf(1.061405429f, t, -1.453152027f);
    p = fmaf(p, t, 1.421413741f);
    p = fmaf(p, t, -0.284496736f);
    p = fmaf(p, t, 0.254829592f);
    p = p * t;
    const float e = __expf(-x * x);
    const float er = fmaf(-p, e, 1.0f);
    const float s = copysignf(er, v);
    return 0.5f * v * (1.0f + s);
}

__device__ __forceinline__ void async_cp16(u16* lds, const u16* g) {
    __builtin_amdgcn_global_load_lds(
        (const __attribute__((address_space(1))) u32*)g,
        (__attribute__((address_space(3))) u32*)lds,
        16, 0, 0);
}

// ---------------- kernel 1: partial group stats ----------------
__global__ __launch_bounds__(256) void gn_stats_partial(const float* __restrict__ x,
                                                        float* __restrict__ pstats) {
    const int bx = blockIdx.x;  // bg*8 + slice
    const float4* p = (const float4*)(x + (size_t)(bx >> 3) * 262144 + (size_t)(bx & 7) * 32768);
    float s = 0.f, ss = 0.f;
    for (int i = threadIdx.x; i < 8192; i += 256) {
        float4 v = p[i];
        s += v.x + v.y + v.z + v.w;
        ss += v.x * v.x + v.y * v.y + v.z * v.z + v.w * v.w;
    }
#pragma unroll
    for (int off = 32; off > 0; off >>= 1) {
        s  += __shfl_down(s, off, 64);
        ss += __shfl_down(ss, off, 64);
    }
    __shared__ float rs[8];
    const int wv = threadIdx.x >> 6;
    if ((threadIdx.x & 63) == 0) { rs[wv * 2] = s; rs[wv * 2 + 1] = ss; }
    __syncthreads();
    if (threadIdx.x == 0) {
        pstats[bx * 2]     = rs[0] + rs[2] + rs[4] + rs[6];
        pstats[bx * 2 + 1] = rs[1] + rs[3] + rs[5] + rs[7];
    }
}

// ---------------- kernel 2: weights fp32 -> bf16 ----------------
__global__ __launch_bounds__(256) void conv_w(const float* __restrict__ w1,
                                              const float* __restrict__ w2,
                                              u16* __restrict__ wb) {
    const int idx = (blockIdx.x * 256 + threadIdx.x) * 4;  // < 1048576
    const float4 v = (idx < 524288) ? *(const float4*)(w1 + idx)
                                    : *(const float4*)(w2 + (idx - 524288));
    ushort4 o;
    o.x = f2bf(v.x); o.y = f2bf(v.y); o.z = f2bf(v.z); o.w = f2bf(v.w);
    *(ushort4*)(wb + idx) = o;
}

// ---------------- kernel 3: normalize + transpose (fp32 -> bf16) ----------------
__global__ __launch_bounds__(256) void gn_norm_tr(const float* __restrict__ x,
                                                  const float* __restrict__ gamma,
                                                  const float* __restrict__ beta,
                                                  const float* __restrict__ pstats,
                                                  u16* __restrict__ xnT, int b0) {
    __shared__ u16 T[64][72];  // [l][c], c-groups XOR-swizzled by (l>>3)&7
    const int bx = blockIdx.x;
    const int lt = bx & 63, ct = (bx >> 6) & 7, bl = bx >> 9;
    const int b = b0 + bl;
    const int c0 = ct * 64, l0 = lt * 64;
    const int g = c0 >> 6;   // tile spans exactly one group
    float S = 0.f, SS = 0.f;
#pragma unroll
    for (int s2 = 0; s2 < 8; ++s2) {
        S  += pstats[((b * 8 + g) * 8 + s2) * 2];
        SS += pstats[((b * 8 + g) * 8 + s2) * 2 + 1];
    }
    const float inv = 1.f / 262144.f;
    const float mean = S * inv;
    const float var = SS * inv - mean * mean;  // population var (jnp.var)
    const float rstd = rsqrtf(var + 1e-5f);

    const int t = threadIdx.x;
    const int cl = t >> 3;          // 0..31
    const int lo = (t & 7) * 8;     // 8 l's per thread
    const int sw = t & 7;           // == (l>>3)&7 for this thread's l's
#pragma unroll
    for (int h = 0; h < 2; ++h) {
        const int c = c0 + cl + h * 32;
        const float sc = rstd * gamma[c];
        const float sh = beta[c] - mean * sc;
        const float* src = x + ((size_t)(b * 512 + c) * 4096 + l0 + lo);
        float4 a = *(const float4*)src;
        float4 bq = *(const float4*)(src + 4);
        float vv[8] = {a.x, a.y, a.z, a.w, bq.x, bq.y, bq.z, bq.w};
        const int ccol = cl + h * 32;
        const int cg = ccol >> 3, cr = ccol & 7;
#pragma unroll
        for (int q = 0; q < 8; ++q)
            T[lo + q][((cg ^ sw) << 3) + cr] = f2bf(fmaf(vv[q], sc, sh));
    }
    __syncthreads();
    const int ll = t >> 3;
    const int co = (t & 7) * 8, cog = t & 7;
#pragma unroll
    for (int h = 0; h < 2; ++h) {
        const int l = ll + h * 32;
        const uint4* srcv = (const uint4*)&T[l][(cog ^ ((l >> 3) & 7)) << 3];
        *(uint4*)(xnT + ((size_t)(bl * 4096 + l0 + l) * 512 + c0 + co)) = *srcv;
    }
}

// ---------------- 256x256 8-wave GEMM core ----------------
// C[m][n] = sum_k A[m][k]*B[n][k], 256 rows per tile each side, BK=64.
// LDS per op: [buf2][kh2][256 rows][4 slots][8 u16] = 64KB; slot holds k-group
// g2 = slot ^ ((row>>1)&3) within the half (k = tile*64 + kh*32 + g2*8 + 0..7).
// Stage of half (tile,kh,op) = 2 global_load_lds per thread, wave-linear dest.
// Schedule per tile t (4 phases):
//   p1 (kh0, ih0): read af[0..3],bb[0..3]; stage A half (t+1,kh1); bar; MFMA16; bar
//   p2 (kh0, ih1): read af[4..7];          stage B half (t+1,kh1); bar; MFMA16; vmcnt(8); bar
//   p3 (kh1, ih0): read af[0..3],bb[0..3]; stage A half (t+2,kh0); bar; MFMA16; bar
//   p4 (kh1, ih1): read af[4..7];          stage B half (t+2,kh0); bar; MFMA16; vmcnt(8); bar
// Prologue stages (t0,kh0,A/B),(t0,kh1,A/B),(t1,kh0,A/B) = 12 loads, vmcnt(8).
// Counting: at p2-end issued = 12+8t+4, landed >= t's kh1 -> vmcnt(8);
// at p4-end issued = 12+8t+8, landed >= (t+1).kh0 -> vmcnt(8). Never 0 in loop.
// Per-wave VM8 sits BEFORE the phase-closing barrier, so crossing the barrier
// certifies ALL waves' slices of the needed half have landed.
// Tail: stage indices wrap mod NT (NT even -> same parity; dummy loads are
// in-bounds and land in slots never read again).
// After the loop: vmcnt(0) drain -- in-flight LDS-DMA past s_endpgm writes
// into deallocated LDS (suspected cause of R7's container fault).
__device__ __forceinline__ void stage_half(u16* ldsOp, const u16* gOp, int K,
                                           int tile, int kh, int tid) {
    u16* dst = ldsOp + ((tile & 1) * 16384 + kh * 8192);
    const u16* src = gOp + (size_t)tile * BKK + kh * 32;
#pragma unroll
    for (int s = 0; s < 2; ++s) {
        int idx2 = s * 512 + tid;
        int row = idx2 >> 2;
        int g2 = (idx2 & 3) ^ ((row >> 1) & 3);
        async_cp16(dst + idx2 * 8, src + (size_t)row * K + g2 * 8);
    }
}

#define VM8 { asm volatile("s_waitcnt vmcnt(8)" ::: "memory"); \
              __builtin_amdgcn_sched_barrier(0); }

__device__ __forceinline__ void gemm_core256(const u16* __restrict__ Ag,
                                             const u16* __restrict__ Bg,
                                             int K, int NT, floatx4 acc[8][4],
                                             u16* lA, u16* lB,
                                             int wm, int wn, int fr, int quad) {
    const int tid = threadIdx.x;
    const int sl4 = quad ^ ((fr >> 1) & 3);   // read slot: (row>>1)&3 == (fr>>1)&3
    bf16x8 bb[4];

    // prologue: t0 full + t1.kh0
    stage_half(lA, Ag, K, 0, 0, tid); stage_half(lB, Bg, K, 0, 0, tid);
    stage_half(lA, Ag, K, 0, 1, tid); stage_half(lB, Bg, K, 0, 1, tid);
    stage_half(lA, Ag, K, 1, 0, tid); stage_half(lB, Bg, K, 1, 0, tid);
    asm volatile("s_waitcnt vmcnt(8)" ::: "memory");  // t0.kh0 landed
    __builtin_amdgcn_sched_barrier(0);
    __builtin_amdgcn_s_barrier();

#define PHASE(kh_, ih_, STG, DOVM)                                              \
    {                                                                           \
        const u16* bA = lA + ((t & 1) * 16384 + (kh_) * 8192);                  \
        const u16* bB = lB + ((t & 1) * 16384 + (kh_) * 8192);                  \
        bf16x8 af[4];                                                           \
        _Pragma("unroll")                                                       \
        for (int i = 0; i < 4; ++i)                                             \
            af[i] = *(const bf16x8*)(bA + ((((wm + (ih_)*64 + i*16 + fr) << 2) | sl4) * 8)); \
        if ((ih_) == 0) {                                                       \
            _Pragma("unroll")                                                   \
            for (int j = 0; j < 4; ++j)                                         \
                bb[j] = *(const bf16x8*)(bB + ((((wn + j*16 + fr) << 2) | sl4) * 8)); \
        }                                                                       \
        STG;                                                                    \
        __builtin_amdgcn_s_barrier();                                           \
        __builtin_amdgcn_s_setprio(1);                                          \
        _Pragma("unroll")                                                       \
        for (int j = 0; j < 4; ++j) {                                           \
            _Pragma("unroll")                                                   \
            for (int i = 0; i < 4; ++i)                                         \
                acc[(ih_)*4 + i][j] = __builtin_amdgcn_mfma_f32_16x16x32_bf16(  \
                    bb[j], af[i], acc[(ih_)*4 + i][j], 0, 0, 0);                \
        }                                                                       \
        __builtin_amdgcn_s_setprio(0);                                          \
        DOVM;                                                                   \
        __builtin_amdgcn_s_barrier();                                           \
    }

    for (int t = 0; t < NT; ++t) {
        int t1 = t + 1; if (t1 >= NT) t1 -= NT;
        int t2 = t + 2; if (t2 >= NT) t2 -= NT;
        PHASE(0, 0, stage_half(lA, Ag, K, t1, 1, tid), {})
        PHASE(0, 1, stage_half(lB, Bg, K, t1, 1, tid), VM8)
        PHASE(1, 0, stage_half(lA, Ag, K, t2, 0, tid), {})
        PHASE(1, 1, stage_half(lB, Bg, K, t2, 0, tid), VM8)
    }
#undef PHASE
    // Drain all in-flight LDS-DMA before the epilogue / s_endpgm.
    asm volatile("s_waitcnt vmcnt(0)" ::: "memory");
    __builtin_amdgcn_sched_barrier(0);
}

// ---------------- kernel 4: GEMM1 + bias + exact GELU -> h1T (bf16) ----------------
// A = xnT [flat l][512], B = w1b [1024][512]; out h1T [flat l][1024].
__global__ __launch_bounds__(512, 2) void gemm1(const u16* __restrict__ xnT,
                                                const u16* __restrict__ w1b,
                                                const float* __restrict__ b1,
                                                u16* __restrict__ h1T) {
    __shared__ u16 lds[65536];  // 128 KiB: A 64KB | B 64KB
    u16* lA = lds;
    u16* lB = lds + 32768;
    const int bx = blockIdx.x;
    // XCD swizzle: mt = group*8 + xcd; 4 nt's of one mt adjacent (dist 8, same xcd).
    const int xcd = bx & 7;
    const int nt = (bx >> 3) & 3;
    const int mt = (bx >> 5) * 8 + xcd;
    const int tid = threadIdx.x, lane = tid & 63, wid = tid >> 6;
    const int wm = (wid >> 2) * 128, wn = (wid & 3) * 64;
    const int fr = lane & 15, quad = lane >> 4;
    floatx4 acc[8][4];
#pragma unroll
    for (int i = 0; i < 8; ++i)
#pragma unroll
        for (int j = 0; j < 4; ++j) acc[i][j] = (floatx4){0.f, 0.f, 0.f, 0.f};

    gemm_core256(xnT + (size_t)(mt * 256) * 512, w1b + (size_t)(nt * 256) * 512,
                 512, 8, acc, lA, lB, wm, wn, fr, quad);

    // swapped layout: m <- col (fr), n <- row (quad*4 + reg)
    const int mb = mt * 256 + wm + fr;
    const int nb = nt * 256 + wn + quad * 4;
#pragma unroll
    for (int j = 0; j < 4; ++j) {
        const int n0 = nb + j * 16;
        const float4 bv = *(const float4*)(b1 + n0);
#pragma unroll
        for (int i = 0; i < 8; ++i) {
            const int m = mb + i * 16;
            ushort4 o;
            o.x = f2bf(gelu_exact(acc[i][j][0] + bv.x));
            o.y = f2bf(gelu_exact(acc[i][j][1] + bv.y));
            o.z = f2bf(gelu_exact(acc[i][j][2] + bv.z));
            o.w = f2bf(gelu_exact(acc[i][j][3] + bv.w));
            *(ushort4*)(h1T + (size_t)m * 1024 + n0) = o;
        }
    }
}

// ---------------- kernel 5: GEMM2 + bias + residual -> out (fp32) ----------------
// A = w2b [512][1024], B = h1T [flat l][1024]; out[b][c][l] = acc + b2 + x.
__global__ __launch_bounds__(512, 2) void gemm2(const u16* __restrict__ w2b,
                                                const u16* __restrict__ h1T,
                                                const float* __restrict__ b2,
                                                const float* __restrict__ x,
                                                float* __restrict__ out, int b0) {
    __shared__ u16 lds[65536];
    u16* lA = lds;
    u16* lB = lds + 32768;
    const int bx = blockIdx.x;
    // XCD swizzle: nt = group*8 + xcd; the 2 mt's of one nt adjacent (dist 8, same xcd).
    const int xcd = bx & 7;
    const int mt = (bx >> 3) & 1;
    const int nt = (bx >> 4) * 8 + xcd;
    const int tid = threadIdx.x, lane = tid & 63, wid = tid >> 6;
    const int wm = (wid >> 2) * 128, wn = (wid & 3) * 64;
    const int fr = lane & 15, quad = lane >> 4;
    floatx4 acc[8][4];
#pragma unroll
    for (int i = 0; i < 8; ++i)
#pragma unroll
        for (int j = 0; j < 4; ++j) acc[i][j] = (floatx4){0.f, 0.f, 0.f, 0.f};

    gemm_core256(w2b + (size_t)(mt * 256) * 1024, h1T + (size_t)(nt * 256) * 1024,
                 1024, 16, acc, lA, lB, wm, wn, fr, quad);

    const int n0g = b0 * 4096 + nt * 256;  // global flat (b,l); tiles never straddle b
    const int b = n0g >> 12;
    const int l_base = n0g & 4095;
    // swapped layout: m <- col (fr) = channel c, n <- row (quad*4 + reg) = l offset
    const int mb = mt * 256 + wm + fr;
    const int nb = wn + quad * 4;
#pragma unroll
    for (int i = 0; i < 8; ++i) {
        const int m = mb + i * 16;
        const float bv = b2[m];
        const size_t rowoff = ((size_t)(b * 512 + m)) * 4096 + l_base + nb;
#pragma unroll
        for (int j = 0; j < 4; ++j) {
            const float4 xv = *(const float4*)(x + rowoff + j * 16);
            float4 ov;
            ov.x = acc[i][j][0] + bv + xv.x;
            ov.y = acc[i][j][1] + bv + xv.y;
            ov.z = acc[i][j][2] + bv + xv.z;
            ov.w = acc[i][j][3] + bv + xv.w;
            *(float4*)(out + rowoff + j * 16) = ov;
        }
    }
}

extern "C" void kernel_launch(void* const* d_in, const int* in_sizes, int n_in,
                              void* d_out, int out_size, void* d_ws, size_t ws_size,
                              hipStream_t stream) {
    const float* x     = (const float*)d_in[0];
    const float* gamma = (const float*)d_in[1];
    const float* beta  = (const float*)d_in[2];
    const float* w1    = (const float*)d_in[3];
    const float* b1    = (const float*)d_in[4];
    const float* w2    = (const float*)d_in[5];
    const float* b2    = (const float*)d_in[6];
    float* out = (float*)d_out;

    char* ws = (char*)d_ws;
    float* pstats = (float*)ws;                    // 8 KB used
    u16* wb = (u16*)(ws + 65536);                  // 2 MiB: w1b then w2b
    char* chunkbase = ws + 65536 + (2u << 20);
    const size_t fixed = 65536 + (2u << 20);

    // choose smallest chunk count NC so xnT+h1T fit in ws
    const size_t per = (size_t)192 * 1024 * 1024;  // NC=1: 64 MiB xnT + 128 MiB h1T
    int NC = 16;
    if      (ws_size >= fixed + per)      NC = 1;
    else if (ws_size >= fixed + per / 2)  NC = 2;
    else if (ws_size >= fixed + per / 4)  NC = 4;
    else if (ws_size >= fixed + per / 8)  NC = 8;
    const int CB = 16 / NC;                        // batches per chunk
    u16* xnT = (u16*)chunkbase;
    u16* h1T = (u16*)(chunkbase + (size_t)CB * 4096 * 512 * 2);

    gn_stats_partial<<<1024, 256, 0, stream>>>(x, pstats);
    conv_w<<<1024, 256, 0, stream>>>(w1, w2, wb);
    for (int ch = 0; ch < NC; ++ch) {
        const int b0 = ch * CB;
        gn_norm_tr<<<CB * 512, 256, 0, stream>>>(x, gamma, beta, pstats, xnT, b0);
        gemm1<<<CB * 64, 512, 0, stream>>>(xnT, wb, b1, h1T);
        gemm2<<<CB * 32, 512, 0, stream>>>(wb + 524288, h1T, b2, x, out, b0);
    }
}